// Round 3
// baseline (308.980 us; speedup 1.0000x reference)
//
#include <hip/hip_runtime.h>
#include <hip/hip_bf16.h>

typedef __attribute__((ext_vector_type(4))) float f32x4;
typedef __attribute__((ext_vector_type(8))) __bf16 bf16x8;
typedef __attribute__((ext_vector_type(4))) __bf16 bf16x4;

#define MFMA_BF16(a, b, c) __builtin_amdgcn_mfma_f32_16x16x32_bf16((a), (b), (c), 0, 0, 0)

static __device__ __forceinline__ __bf16 f2b(float f) {
    return __builtin_bit_cast(__bf16, __float2bfloat16(f));
}
static __device__ __forceinline__ unsigned short f2u(float f) {
    return __builtin_bit_cast(unsigned short, __float2bfloat16(f));
}

// ---------------- prep: bf16 weights (Q pre-scaled), scaled bias, mask+rpb table ----
// ws layout: wqkv_b [384][128] bf16 @0 ; wproj_b [128][128] bf16 @98304 ;
//            bqkv_s [384] f32 @131072 ; cmb [64][4][2401] f32 @132608
__global__ void prep_kernel(const float* __restrict__ w_qkv, const float* __restrict__ b_qkv,
                            const float* __restrict__ w_proj, const float* __restrict__ mask,
                            const float* __restrict__ table, const int* __restrict__ rel,
                            unsigned short* __restrict__ wqkv_b, unsigned short* __restrict__ wproj_b,
                            float* __restrict__ bqkv_s, float* __restrict__ cmb) {
    const float s = 0.17677669529663687f;  // 32^-0.5
    int i = blockIdx.x * 256 + threadIdx.x;
    if (i < 49152) {
        int n = i >> 7;
        wqkv_b[i] = f2u(w_qkv[i] * (n < 128 ? s : 1.0f));
    } else if (i < 49536) {
        int j = i - 49152;
        bqkv_s[j] = b_qkv[j] * (j < 128 ? s : 1.0f);
    } else if (i < 65920) {
        int e = i - 49536;
        wproj_b[e] = f2u(w_proj[e]);
    } else if (i < 680576) {
        int c = i - 65920;
        int wi = c / 9604;
        int r2 = c - wi * 9604;
        int h = r2 / 2401;
        int mn = r2 - h * 2401;
        cmb[c] = mask[wi * 2401 + mn] + table[rel[mn] * 4 + h];
    }
}

// ---------------- fully fused: QKV-proj + window attention + out-proj ----------------
// 1 block / window (4 waves = 4 heads). LDS 64 KB:
//   [0,16384)       Xs[64][128] bf16 swz((t&7)<<4)  -> reused as Os after sync2
//   [16384,49152)   per head h (8 KB): Q[64][32] swz((t&3)<<4) @+0, K @+4096;
//                   P[64][64] swz((m&7)<<4) overlays own Q+K (same-wave ordering)
//   [49152,65536)   per head h (4 KB): Vt[32][64] swz((d&7)<<4)
__global__ __launch_bounds__(256, 2) void fused_kernel(
    const float* __restrict__ x, const unsigned short* __restrict__ wqkv_b,
    const float* __restrict__ bqkv_s, const unsigned short* __restrict__ wproj_b,
    const float* __restrict__ b_proj, const float* __restrict__ cmb,
    float* __restrict__ out) {
    __shared__ __align__(16) char smem[65536];

    const int b = blockIdx.x;
    const int tid = threadIdx.x;
    const int lane = tid & 63;
    const int h = tid >> 6;
    const int wi = b & 63;

    char* xos = smem;                       // Xs / Os
    char* qkp = smem + 16384 + h * 8192;    // Q @+0, K @+4096, P overlays
    char* vts = smem + 49152 + h * 4096;    // Vt

    // ---- phase A: stage x -> Xs (bf16, rows 49..63 zero) ----
    {
        const float* xb = x + (size_t)b * 49 * 128;
        for (int i = tid; i < 2048; i += 256) {
            int row = i >> 5, c4 = (i & 31) * 4;
            float4 v = {0.f, 0.f, 0.f, 0.f};
            if (row < 49) v = *(const float4*)(xb + row * 128 + c4);
            bf16x4 bv = {f2b(v.x), f2b(v.y), f2b(v.z), f2b(v.w)};
            *(bf16x4*)(xos + row * 256 + ((c4 * 2) ^ ((row & 7) << 4))) = bv;
        }
    }
    __syncthreads();  // sync1: Xs ready

    const int rb = (lane >> 4) * 4;
    const int cI = lane & 15;

    // ---- phase B: QKV projection for this head's 96 channels ----
    {
        bf16x8 af[4][4];
#pragma unroll
        for (int mt = 0; mt < 4; ++mt)
#pragma unroll
            for (int kc = 0; kc < 4; ++kc) {
                int row = mt * 16 + cI;
                af[mt][kc] = *(const bf16x8*)(xos + row * 256 +
                                              ((kc * 64 + (lane >> 4) * 16) ^ ((row & 7) << 4)));
            }
#pragma unroll
        for (int ct = 0; ct < 6; ++ct) {
            int n0 = (ct < 2) ? h * 32 + ct * 16
                              : (ct < 4) ? 128 + h * 32 + (ct - 2) * 16
                                         : 256 + h * 32 + (ct - 4) * 16;
            bf16x8 bfr[4];
#pragma unroll
            for (int kc = 0; kc < 4; ++kc)
                bfr[kc] = *(const bf16x8*)(wqkv_b + (size_t)(n0 + cI) * 128 + kc * 32 +
                                           (lane >> 4) * 8);
            f32x4 acc[4] = {};
#pragma unroll
            for (int mt = 0; mt < 4; ++mt)
#pragma unroll
                for (int kc = 0; kc < 4; ++kc)
                    acc[mt] = MFMA_BF16(af[mt][kc], bfr[kc], acc[mt]);
            float bias = bqkv_s[n0 + cI];
            if (ct < 4) {  // Q or K: scalar bf16 writes, [t][d] swz((t&3)<<4)
                char* base = qkp + ((ct < 2) ? 0 : 4096);
                int d = (ct & 1) * 16 + cI;
#pragma unroll
                for (int mt = 0; mt < 4; ++mt)
#pragma unroll
                    for (int r = 0; r < 4; ++r) {
                        int t = mt * 16 + rb + r;
                        *(__bf16*)(base + t * 64 + ((d * 2) ^ ((t & 3) << 4))) =
                            f2b(acc[mt][r] + bias);
                    }
            } else {  // V: transposed [d][t], 4 consecutive t -> 8B write
                int d = (ct & 1) * 16 + cI;
#pragma unroll
                for (int mt = 0; mt < 4; ++mt) {
                    int t0 = mt * 16 + rb;
                    bf16x4 pv = {f2b(acc[mt][0] + bias), f2b(acc[mt][1] + bias),
                                 f2b(acc[mt][2] + bias), f2b(acc[mt][3] + bias)};
                    *(bf16x4*)(vts + d * 128 + ((t0 * 2) ^ ((d & 7) << 4))) = pv;
                }
            }
        }
    }
    __syncthreads();  // sync2: Q/K/Vt ready; everyone done reading Xs

    // ---- phase C: S = Qhat.K^T + cmb ; softmax ----
    f32x4 S[4][4] = {};
    {
        bf16x8 qf[4], kf[4];
#pragma unroll
        for (int mt = 0; mt < 4; ++mt) {
            int row = mt * 16 + cI;
            qf[mt] = *(const bf16x8*)(qkp + row * 64 + (((lane >> 4) * 16) ^ ((row & 3) << 4)));
        }
#pragma unroll
        for (int nt = 0; nt < 4; ++nt) {
            int row = nt * 16 + cI;
            kf[nt] = *(const bf16x8*)(qkp + 4096 + row * 64 +
                                      (((lane >> 4) * 16) ^ ((row & 3) << 4)));
        }
#pragma unroll
        for (int mt = 0; mt < 4; ++mt)
#pragma unroll
            for (int nt = 0; nt < 4; ++nt)
                S[mt][nt] = MFMA_BF16(qf[mt], kf[nt], S[mt][nt]);
    }
    {
        const float* cw = cmb + ((size_t)wi * 4 + h) * 2401;
#pragma unroll
        for (int mt = 0; mt < 4; ++mt)
#pragma unroll
            for (int nt = 0; nt < 4; ++nt)
#pragma unroll
                for (int r = 0; r < 4; ++r) {
                    int m = mt * 16 + rb + r, n = nt * 16 + cI;
                    if (m < 49 && n < 49)
                        S[mt][nt][r] += cw[m * 49 + n];
                    else
                        S[mt][nt][r] = -1e30f;
                }
    }
    float sm[4][4];
#pragma unroll
    for (int mt = 0; mt < 4; ++mt)
#pragma unroll
        for (int r = 0; r < 4; ++r) {
            float v = fmaxf(fmaxf(S[mt][0][r], S[mt][1][r]), fmaxf(S[mt][2][r], S[mt][3][r]));
            v = fmaxf(v, __shfl_xor(v, 1));
            v = fmaxf(v, __shfl_xor(v, 2));
            v = fmaxf(v, __shfl_xor(v, 4));
            v = fmaxf(v, __shfl_xor(v, 8));
            sm[mt][r] = v;  // row max for now
        }
#pragma unroll
    for (int mt = 0; mt < 4; ++mt)
#pragma unroll
        for (int nt = 0; nt < 4; ++nt)
#pragma unroll
            for (int r = 0; r < 4; ++r)
                S[mt][nt][r] = __expf(S[mt][nt][r] - sm[mt][r]);
#pragma unroll
    for (int mt = 0; mt < 4; ++mt)
#pragma unroll
        for (int r = 0; r < 4; ++r) {
            float v = S[mt][0][r] + S[mt][1][r] + S[mt][2][r] + S[mt][3][r];
            v += __shfl_xor(v, 1);
            v += __shfl_xor(v, 2);
            v += __shfl_xor(v, 4);
            v += __shfl_xor(v, 8);
            sm[mt][r] = 1.0f / v;  // applied after PV (linear)
        }
    // write P (unnormalized bf16) over own Q+K region — same-wave LDS ordering
#pragma unroll
    for (int mt = 0; mt < 4; ++mt)
#pragma unroll
        for (int nt = 0; nt < 4; ++nt)
#pragma unroll
            for (int r = 0; r < 4; ++r) {
                int m = mt * 16 + rb + r, n = nt * 16 + cI;
                *(__bf16*)(qkp + m * 128 + ((n * 2) ^ ((m & 7) << 4))) = f2b(S[mt][nt][r]);
            }

    // ---- phase D: O = P.V ----
    f32x4 Oa[4][2] = {};
#pragma unroll
    for (int kt = 0; kt < 2; ++kt) {
        const int kb = kt * 64 + (lane >> 4) * 16;
        bf16x8 pf[4], vf[2];
#pragma unroll
        for (int mt = 0; mt < 4; ++mt) {
            int row = mt * 16 + cI;
            pf[mt] = *(const bf16x8*)(qkp + row * 128 + (kb ^ ((row & 7) << 4)));
        }
#pragma unroll
        for (int nd = 0; nd < 2; ++nd) {
            int row = nd * 16 + cI;
            vf[nd] = *(const bf16x8*)(vts + row * 128 + (kb ^ ((row & 7) << 4)));
        }
#pragma unroll
        for (int mt = 0; mt < 4; ++mt)
#pragma unroll
            for (int nd = 0; nd < 2; ++nd)
                Oa[mt][nd] = MFMA_BF16(pf[mt], vf[nd], Oa[mt][nd]);
    }

    // ---- phase E: normalize, write Os (over Xs region) ----
#pragma unroll
    for (int mt = 0; mt < 4; ++mt)
#pragma unroll
        for (int nd = 0; nd < 2; ++nd)
#pragma unroll
            for (int r = 0; r < 4; ++r) {
                int t = mt * 16 + rb + r;
                int c = h * 32 + nd * 16 + cI;
                *(__bf16*)(xos + t * 256 + ((c * 2) ^ ((t & 7) << 4))) =
                    f2b(Oa[mt][nd][r] * sm[mt][r]);
            }
    __syncthreads();  // sync3: Os ready

    // ---- phase F: out-proj, wave h -> output cols [h*32, h*32+32) ----
    {
        bf16x8 af[4][4];
#pragma unroll
        for (int mt = 0; mt < 4; ++mt)
#pragma unroll
            for (int kc = 0; kc < 4; ++kc) {
                int row = mt * 16 + cI;
                af[mt][kc] = *(const bf16x8*)(xos + row * 256 +
                                              ((kc * 64 + (lane >> 4) * 16) ^ ((row & 7) << 4)));
            }
#pragma unroll
        for (int ct = 0; ct < 2; ++ct) {
            int n0 = h * 32 + ct * 16;
            bf16x8 bfr[4];
#pragma unroll
            for (int kc = 0; kc < 4; ++kc)
                bfr[kc] = *(const bf16x8*)(wproj_b + (size_t)(n0 + cI) * 128 + kc * 32 +
                                           (lane >> 4) * 8);
            f32x4 acc[4] = {};
#pragma unroll
            for (int mt = 0; mt < 4; ++mt)
#pragma unroll
                for (int kc = 0; kc < 4; ++kc)
                    acc[mt] = MFMA_BF16(af[mt][kc], bfr[kc], acc[mt]);
            float bias = b_proj[n0 + cI];
#pragma unroll
            for (int mt = 0; mt < 4; ++mt)
#pragma unroll
                for (int r = 0; r < 4; ++r) {
                    int t = mt * 16 + rb + r;
                    if (t < 49)
                        out[((size_t)b * 49 + t) * 128 + n0 + cI] = acc[mt][r] + bias;
                }
        }
    }
}

extern "C" void kernel_launch(void* const* d_in, const int* in_sizes, int n_in,
                              void* d_out, int out_size, void* d_ws, size_t ws_size,
                              hipStream_t stream) {
    (void)in_sizes; (void)n_in; (void)out_size; (void)ws_size;
    const float* x      = (const float*)d_in[0];
    const float* mask   = (const float*)d_in[1];
    const float* w_qkv  = (const float*)d_in[2];
    const float* b_qkv  = (const float*)d_in[3];
    const float* w_proj = (const float*)d_in[4];
    const float* b_proj = (const float*)d_in[5];
    const float* btab   = (const float*)d_in[6];
    const int*   rel    = (const int*)d_in[7];
    float* out = (float*)d_out;

    char* ws = (char*)d_ws;
    unsigned short* wqkv_b  = (unsigned short*)(ws);           //  98,304 B
    unsigned short* wproj_b = (unsigned short*)(ws + 98304);   //  32,768 B
    float*          bqkv_s  = (float*)(ws + 131072);           //   1,536 B
    float*          cmb     = (float*)(ws + 132608);           // 2,458,624 B  (total ~2.6 MB)

    prep_kernel<<<2659, 256, 0, stream>>>(w_qkv, b_qkv, w_proj, mask, btab, rel,
                                          wqkv_b, wproj_b, bqkv_s, cmb);
    fused_kernel<<<4096, 256, 0, stream>>>(x, wqkv_b, bqkv_s, wproj_b, b_proj, cmb, out);
}

// Round 5
// 294.511 us; speedup vs baseline: 1.0491x; 1.0491x over previous
//
#include <hip/hip_runtime.h>
#include <hip/hip_bf16.h>

typedef __attribute__((ext_vector_type(4))) float f32x4;
typedef __attribute__((ext_vector_type(8))) __bf16 bf16x8;
typedef __attribute__((ext_vector_type(4))) __bf16 bf16x4;

#define MFMA_BF16(a, b, c) __builtin_amdgcn_mfma_f32_16x16x32_bf16((a), (b), (c), 0, 0, 0)

static __device__ __forceinline__ __bf16 f2b(float f) {
    return __builtin_bit_cast(__bf16, __float2bfloat16(f));
}
static __device__ __forceinline__ unsigned short f2u(float f) {
    return __builtin_bit_cast(unsigned short, __float2bfloat16(f));
}

// ---------------- prep: bf16 weights (Q pre-scaled), scaled bias, mask+rpb table ----
__global__ void prep_kernel(const float* __restrict__ w_qkv, const float* __restrict__ b_qkv,
                            const float* __restrict__ w_proj, const float* __restrict__ mask,
                            const float* __restrict__ table, const int* __restrict__ rel,
                            unsigned short* __restrict__ wqkv_b, unsigned short* __restrict__ wproj_b,
                            float* __restrict__ bqkv_s, float* __restrict__ cmb) {
    const float s = 0.17677669529663687f;  // 32^-0.5
    int i = blockIdx.x * 256 + threadIdx.x;
    if (i < 49152) {
        int n = i >> 7;
        wqkv_b[i] = f2u(w_qkv[i] * (n < 128 ? s : 1.0f));
    } else if (i < 49536) {
        int j = i - 49152;
        bqkv_s[j] = b_qkv[j] * (j < 128 ? s : 1.0f);
    } else if (i < 65920) {
        int e = i - 49536;
        wproj_b[e] = f2u(w_proj[e]);
    } else if (i < 680576) {
        int c = i - 65920;
        int wi = c / 9604;
        int r2 = c - wi * 9604;
        int h = r2 / 2401;
        int mn = r2 - h * 2401;
        cmb[c] = mask[wi * 2401 + mn] + table[rel[mn] * 4 + h];
    }
}

// Q/K LDS address: global-XOR swizzle over [64][32] bf16 (64-B rows).
// Bijective (addr bit6 = t bit0, XORed with t bit2); ds_read_b128 of rows 0..15 at
// fixed off covers all 32 banks with 2 lanes/bank (conflict-free per m136).
static __device__ __forceinline__ int qk_addr(int t, int off) {
    return (t * 64 + off) ^ ((t & 7) << 4);
}

// ---------------- fully fused: QKV-proj + window attention + out-proj ----------------
// 1 block / window, 512 threads = 8 waves; wave w: head h=w>>1, q-half q=w&1.
// LDS 64 KB: Xs[64][128] bf16 swz((t&7)<<4) @0 (reused as Os);
//   per head h @16384+h*12288: Q[64][32] @+0, K @+4096 (qk_addr), Vt[32][64] @+8192
//   swz((d&7)<<4); P[64][64] swz((m&7)<<4) overlays Q+K (barrier-protected).
__global__ __launch_bounds__(512, 4) void fused_kernel(
    const float* __restrict__ x, const unsigned short* __restrict__ wqkv_b,
    const float* __restrict__ bqkv_s, const unsigned short* __restrict__ wproj_b,
    const float* __restrict__ b_proj, const float* __restrict__ cmb,
    float* __restrict__ out) {
    __shared__ __align__(16) char smem[65536];

    const int b = blockIdx.x;
    const int tid = threadIdx.x;
    const int lane = tid & 63;
    const int w = tid >> 6;       // wave 0..7
    const int h = w >> 1;         // head
    const int q = w & 1;          // query-half (rows [32q, 32q+32))
    const int wi = b & 63;

    char* xos = smem;                          // Xs / Os [64][128] bf16
    char* qkp = smem + 16384 + h * 12288;      // Q @+0, K @+4096 (P overlays), Vt @+8192
    char* vts = qkp + 8192;

    const int rb = (lane >> 4) * 4;
    const int cI = lane & 15;

    // ---- phase A: stage x -> Xs (bf16, rows 49..63 zero) ----
    {
        const float* xb = x + (size_t)b * 49 * 128;
        for (int i = tid; i < 2048; i += 512) {
            int row = i >> 5, c4 = (i & 31) * 4;
            float4 v = {0.f, 0.f, 0.f, 0.f};
            if (row < 49) v = *(const float4*)(xb + row * 128 + c4);
            bf16x4 bv = {f2b(v.x), f2b(v.y), f2b(v.z), f2b(v.w)};
            *(bf16x4*)(xos + row * 256 + ((c4 * 2) ^ ((row & 7) << 4))) = bv;
        }
    }
    __syncthreads();  // sync1: Xs ready

    // ---- phase B: QKV projection; wave w does tiles n0 = t3*128 + w*16, t3=0(Q),1(K),2(V) ----
    {
        bf16x8 af[4][4];
#pragma unroll
        for (int mt = 0; mt < 4; ++mt)
#pragma unroll
            for (int kc = 0; kc < 4; ++kc) {
                int row = mt * 16 + cI;
                af[mt][kc] = *(const bf16x8*)(xos + row * 256 +
                                              ((kc * 64 + (lane >> 4) * 16) ^ ((row & 7) << 4)));
            }
#pragma unroll
        for (int t3 = 0; t3 < 3; ++t3) {
            int n0 = t3 * 128 + w * 16;
            bf16x8 bfr[4];
#pragma unroll
            for (int kc = 0; kc < 4; ++kc)
                bfr[kc] = *(const bf16x8*)(wqkv_b + (size_t)(n0 + cI) * 128 + kc * 32 +
                                           (lane >> 4) * 8);
            f32x4 acc[4] = {};
#pragma unroll
            for (int mt = 0; mt < 4; ++mt)
#pragma unroll
                for (int kc = 0; kc < 4; ++kc)
                    acc[mt] = MFMA_BF16(af[mt][kc], bfr[kc], acc[mt]);
            float bias = bqkv_s[n0 + cI];
            int dl = q * 16 + cI;  // in-head channel 0..31
            if (t3 < 2) {          // Q or K: [t][d] qk_addr, scalar bf16 writes
                char* base = qkp + t3 * 4096;
#pragma unroll
                for (int mt = 0; mt < 4; ++mt)
#pragma unroll
                    for (int r = 0; r < 4; ++r) {
                        int t = mt * 16 + rb + r;
                        *(__bf16*)(base + qk_addr(t, dl * 2)) = f2b(acc[mt][r] + bias);
                    }
            } else {  // V transposed [d][t] swz((d&7)<<4), 4 consecutive t -> 8B write
#pragma unroll
                for (int mt = 0; mt < 4; ++mt) {
                    int t0 = mt * 16 + rb;
                    bf16x4 pv = {f2b(acc[mt][0] + bias), f2b(acc[mt][1] + bias),
                                 f2b(acc[mt][2] + bias), f2b(acc[mt][3] + bias)};
                    *(bf16x4*)(vts + dl * 128 + ((t0 * 2) ^ ((dl & 7) << 4))) = pv;
                }
            }
        }
    }
    __syncthreads();  // sync2: Q/K/Vt ready; all waves done reading Xs

    // ---- phase C: S = Qhat.K^T + cmb ; softmax (rows [32q, 32q+32)) ----
    f32x4 S[2][4] = {};
    {
        bf16x8 qf[2], kf[4];
#pragma unroll
        for (int j = 0; j < 2; ++j) {
            int row = (2 * q + j) * 16 + cI;
            qf[j] = *(const bf16x8*)(qkp + qk_addr(row, (lane >> 4) * 16));
        }
#pragma unroll
        for (int nt = 0; nt < 4; ++nt) {
            int row = nt * 16 + cI;
            kf[nt] = *(const bf16x8*)(qkp + 4096 + qk_addr(row, (lane >> 4) * 16));
        }
#pragma unroll
        for (int j = 0; j < 2; ++j)
#pragma unroll
            for (int nt = 0; nt < 4; ++nt)
                S[j][nt] = MFMA_BF16(qf[j], kf[nt], S[j][nt]);
    }
    __syncthreads();  // sync3 (RACE FIX): all waves' Q/K fragment reads are complete
                      // before any wave's P write overlays the Q/K buffers below.
    {
        const float* cw = cmb + ((size_t)wi * 4 + h) * 2401;
#pragma unroll
        for (int j = 0; j < 2; ++j)
#pragma unroll
            for (int nt = 0; nt < 4; ++nt)
#pragma unroll
                for (int r = 0; r < 4; ++r) {
                    int m = (2 * q + j) * 16 + rb + r, n = nt * 16 + cI;
                    if (m < 49 && n < 49)
                        S[j][nt][r] += cw[m * 49 + n];
                    else
                        S[j][nt][r] = -1e30f;
                }
    }
    float sm[2][4];
#pragma unroll
    for (int j = 0; j < 2; ++j)
#pragma unroll
        for (int r = 0; r < 4; ++r) {
            float v = fmaxf(fmaxf(S[j][0][r], S[j][1][r]), fmaxf(S[j][2][r], S[j][3][r]));
            v = fmaxf(v, __shfl_xor(v, 1));
            v = fmaxf(v, __shfl_xor(v, 2));
            v = fmaxf(v, __shfl_xor(v, 4));
            v = fmaxf(v, __shfl_xor(v, 8));
            sm[j][r] = v;
        }
#pragma unroll
    for (int j = 0; j < 2; ++j)
#pragma unroll
        for (int nt = 0; nt < 4; ++nt)
#pragma unroll
            for (int r = 0; r < 4; ++r)
                S[j][nt][r] = __expf(S[j][nt][r] - sm[j][r]);
#pragma unroll
    for (int j = 0; j < 2; ++j)
#pragma unroll
        for (int r = 0; r < 4; ++r) {
            float v = S[j][0][r] + S[j][1][r] + S[j][2][r] + S[j][3][r];
            v += __shfl_xor(v, 1);
            v += __shfl_xor(v, 2);
            v += __shfl_xor(v, 4);
            v += __shfl_xor(v, 8);
            sm[j][r] = 1.0f / v;  // applied after PV (linear)
        }
    // write P rows [32q,+32) (unnormalized bf16) over own head's Q+K region
#pragma unroll
    for (int j = 0; j < 2; ++j)
#pragma unroll
        for (int nt = 0; nt < 4; ++nt)
#pragma unroll
            for (int r = 0; r < 4; ++r) {
                int m = (2 * q + j) * 16 + rb + r, n = nt * 16 + cI;
                *(__bf16*)(qkp + m * 128 + ((n * 2) ^ ((m & 7) << 4))) = f2b(S[j][nt][r]);
            }

    // ---- phase D: O = P.V (rows [32q,+32), all 32 d) ----
    f32x4 Oa[2][2] = {};
#pragma unroll
    for (int kt = 0; kt < 2; ++kt) {
        const int kb = kt * 64 + (lane >> 4) * 16;
        bf16x8 pf[2], vf[2];
#pragma unroll
        for (int j = 0; j < 2; ++j) {
            int row = (2 * q + j) * 16 + cI;
            pf[j] = *(const bf16x8*)(qkp + row * 128 + (kb ^ ((row & 7) << 4)));
        }
#pragma unroll
        for (int nd = 0; nd < 2; ++nd) {
            int row = nd * 16 + cI;
            vf[nd] = *(const bf16x8*)(vts + row * 128 + (kb ^ ((row & 7) << 4)));
        }
#pragma unroll
        for (int j = 0; j < 2; ++j)
#pragma unroll
            for (int nd = 0; nd < 2; ++nd)
                Oa[j][nd] = MFMA_BF16(pf[j], vf[nd], Oa[j][nd]);
    }

    // ---- phase E: normalize, write Os rows [32q,+32), cols [32h,+32) (over Xs) ----
#pragma unroll
    for (int j = 0; j < 2; ++j)
#pragma unroll
        for (int nd = 0; nd < 2; ++nd)
#pragma unroll
            for (int r = 0; r < 4; ++r) {
                int t = (2 * q + j) * 16 + rb + r;
                int c = h * 32 + nd * 16 + cI;
                *(__bf16*)(xos + t * 256 + ((c * 2) ^ ((t & 7) << 4))) =
                    f2b(Oa[j][nd][r] * sm[j][r]);
            }
    __syncthreads();  // sync4: Os ready

    // ---- phase F: out-proj; wave w -> output cols [w*16, w*16+16) ----
    {
        bf16x8 af[4][4];
#pragma unroll
        for (int mt = 0; mt < 4; ++mt)
#pragma unroll
            for (int kc = 0; kc < 4; ++kc) {
                int row = mt * 16 + cI;
                af[mt][kc] = *(const bf16x8*)(xos + row * 256 +
                                              ((kc * 64 + (lane >> 4) * 16) ^ ((row & 7) << 4)));
            }
        int n0 = w * 16;
        bf16x8 bfr[4];
#pragma unroll
        for (int kc = 0; kc < 4; ++kc)
            bfr[kc] = *(const bf16x8*)(wproj_b + (size_t)(n0 + cI) * 128 + kc * 32 +
                                       (lane >> 4) * 8);
        f32x4 acc[4] = {};
#pragma unroll
        for (int mt = 0; mt < 4; ++mt)
#pragma unroll
            for (int kc = 0; kc < 4; ++kc)
                acc[mt] = MFMA_BF16(af[mt][kc], bfr[kc], acc[mt]);
        float bias = b_proj[n0 + cI];
#pragma unroll
        for (int mt = 0; mt < 4; ++mt)
#pragma unroll
            for (int r = 0; r < 4; ++r) {
                int t = mt * 16 + rb + r;
                if (t < 49)
                    out[((size_t)b * 49 + t) * 128 + n0 + cI] = acc[mt][r] + bias;
            }
    }
}

extern "C" void kernel_launch(void* const* d_in, const int* in_sizes, int n_in,
                              void* d_out, int out_size, void* d_ws, size_t ws_size,
                              hipStream_t stream) {
    (void)in_sizes; (void)n_in; (void)out_size; (void)ws_size;
    const float* x      = (const float*)d_in[0];
    const float* mask   = (const float*)d_in[1];
    const float* w_qkv  = (const float*)d_in[2];
    const float* b_qkv  = (const float*)d_in[3];
    const float* w_proj = (const float*)d_in[4];
    const float* b_proj = (const float*)d_in[5];
    const float* btab   = (const float*)d_in[6];
    const int*   rel    = (const int*)d_in[7];
    float* out = (float*)d_out;

    char* ws = (char*)d_ws;
    unsigned short* wqkv_b  = (unsigned short*)(ws);           //  98,304 B
    unsigned short* wproj_b = (unsigned short*)(ws + 98304);   //  32,768 B
    float*          bqkv_s  = (float*)(ws + 131072);           //   1,536 B
    float*          cmb     = (float*)(ws + 132608);           // 2,458,624 B (total ~2.6 MB)

    prep_kernel<<<2659, 256, 0, stream>>>(w_qkv, b_qkv, w_proj, mask, btab, rel,
                                          wqkv_b, wproj_b, bqkv_s, cmb);
    fused_kernel<<<4096, 512, 0, stream>>>(x, wqkv_b, bqkv_s, wproj_b, b_proj, cmb, out);
}